// Round 4
// baseline (173.622 us; speedup 1.0000x reference)
//
#include <hip/hip_runtime.h>

// DigiCaps dynamic routing — R23: 4-i tiles, 2304 blocks (2x R18).
// inputs [512,1152,8] f32, W [10,1152,16,8] f32, out v [512,10,16] f32.
// u_hat[b,j,i,d] = sum_k x[b,i,k] W[j,i,d,k]; logits via vsum recurrence;
// u_hat never materialized (3 recompute passes).
//
// Evidence trail:
//  R20: reg-held prefetch -> spill (FETCH 338MB).   [artifact]
//  R21: (512,4) VGPR cap 64 -> spill (FETCH 266MB). [artifact]
//  R22: NLOOP=4, 288 blocks -> caps ~44us, total 173 (worse): fewer
//       blocks = worse. Pass time tracks BLOCK COUNT, not per-block work.
// R23: halve the i-tile (8->4), double blocks to (8,288)=2304 at constant
// block shape (4 waves, 256 thr). Per-block chain halves (one K=32 unit);
// codegen is a strict subset of proven R18 (t4 dimension removed) -> VGPR
// ~104 expected (spill gate: VGPR==104, FETCH ~16-18MB).
// Cost: part = [288][512][160] bf16 = 47MB (+24MB write/pass, +24MB squash
// read). W/x read traffic unchanged (tile halves x blocks double).
// Carried from prior session (518 -> 156 us):
//  - MFMA f32_16x16x32_bf16; C-layout lane&15=b, (lane>>4)*4+reg=d.
//  - A-frags K=32-packed; MODE0 contracts 4 i's/MFMA; MODE1 masks B per q.
//  - bf16 tiles pre-converted once; LDS stage via plain loads+ds_write.
//  - (256,2) launch bounds = proven no-spill point.
//  - Epilogue: LDS bounce -> dense contiguous bf16 partials.
//  - fp16x2-packed logit butterfly (10 shfl + 10 pk_add), no max-subtract.
// absmax prior 3.9e-3 (threshold 17.5e-3).

#define NB 512
#define NI 1152
#define NJ 10
#define ND 16
#define NIG4 288   // i-groups of 4

typedef short          bf16x8 __attribute__((ext_vector_type(8)));
typedef unsigned short u16x8  __attribute__((ext_vector_type(8)));
typedef float          f32x4  __attribute__((ext_vector_type(4)));
typedef __fp16         h16x2  __attribute__((ext_vector_type(2)));

constexpr float EPS_ = 1e-7f;

constexpr size_t XB_ELEMS = (size_t)NB * NI * 8;       // bf16
constexpr size_t WB_ELEMS = (size_t)NJ * NI * ND * 8;  // bf16
constexpr int    XQ = 1179648;                         // x float4 quads
constexpr int    WQ = 368640;                          // W float4 quads

__device__ inline unsigned short f2bf(float f) {   // RNE f32->bf16
    unsigned u = __float_as_uint(f);
    return (unsigned short)((u + 0x7fffu + ((u >> 16) & 1u)) >> 16);
}
__device__ inline float bf2f(unsigned short u) {
    return __uint_as_float((unsigned)u << 16);
}

__global__ __launch_bounds__(256)
void conv_bf16(const float* __restrict__ x, const float* __restrict__ Wg,
               unsigned short* __restrict__ xb, unsigned short* __restrict__ wb)
{
    int t = blockIdx.x * 256 + threadIdx.x;
    if (t < XQ) {
        float4 v = ((const float4*)x)[t];
        ushort4 o; o.x=f2bf(v.x); o.y=f2bf(v.y); o.z=f2bf(v.z); o.w=f2bf(v.w);
        ((ushort4*)xb)[t] = o;
    } else if (t - XQ < WQ) {
        int u = t - XQ;
        float4 v = ((const float4*)Wg)[u];
        ushort4 o; o.x=f2bf(v.x); o.y=f2bf(v.y); o.z=f2bf(v.z); o.w=f2bf(v.w);
        ((ushort4*)wb)[u] = o;
    }
}

// Block: 64 b (4 waves x 16) x 4 i (one K=32 pack). LDS 21504B (epilogue
// bounce is the max: s16[64][168]).
template <int MODE>
__global__ __launch_bounds__(256, 2)
void caps_pass(const unsigned short* __restrict__ xb,
               const unsigned short* __restrict__ wb,
               const float* __restrict__ vsum_g,
               unsigned short* __restrict__ part)
{
    // wl: granule g = il*161 + j*16 + d (161-pad breaks kg-group aliasing,
    // proven). xl: row stride 5 granules (4 il + pad). Epilogue reuses smem
    // as bf16 s16[64][168] = 21504 B (the sizing term).
    __shared__ __align__(16) char smem[21504];
    unsigned short* wl = (unsigned short*)smem;                 // 644 granules
    unsigned short* xl = (unsigned short*)(smem + 10304);       // 320 granules

    const int tid = threadIdx.x, lane = tid & 63, w = tid >> 6;
    const int bl = lane & 15, kg = lane >> 4;
    const int bg = blockIdx.x, ig = blockIdx.y;
    const int i0 = ig * 4, b0 = bg * 64;
    const int b  = b0 + w * 16 + bl;
    const int brow = w * 16 + bl;

    // stage W: 640 real granules -> slot il*161 + rem  (2.5 rounds)
#pragma unroll
    for (int r = 0; r < 3; ++r) {
        int g = tid + r * 256;
        if (r < 2 || tid < 128) {
            int il = g / 160, rem = g - il * 160;
            const unsigned short* src =
                wb + ((size_t)(rem >> 4) * NI + (i0 + il)) * 128 + (rem & 15) * 8;
            *(u16x8*)(wl + (il * 161 + rem) * 8) = *(const u16x8*)src;
        }
    }
    // stage x: slot brr*5 + il  <-  x[b0+brr, i0+il, 0:8]  (256 granules)
    {
        int g = tid;
        int brr = g >> 2, il = g & 3;
        *(u16x8*)(xl + (brr * 5 + il) * 8) =
            *(const u16x8*)(xb + ((size_t)(b0 + brr) * NI + i0 + il) * 8);
    }

    f32x4 vs[NJ];
    if (MODE == 1) {
#pragma unroll
        for (int j = 0; j < NJ; ++j)
            vs[j] = *(const f32x4*)(vsum_g + (size_t)b * 160 + j * 16 + kg * 4);
    }

    __syncthreads();

    const f32x4  zero  = {0.f, 0.f, 0.f, 0.f};
    const bf16x8 zerob = {0, 0, 0, 0, 0, 0, 0, 0};
    f32x4 sacc[NJ];
#pragma unroll
    for (int j = 0; j < NJ; ++j) sacc[j] = zero;

    // A-frags: lane (kg,bl) = W[i0+kg, j, d=bl, 0:8] — K=32 packed,
    // all 64 lanes real; 10 reads for FOUR i's.
    bf16x8 afull[NJ];
#pragma unroll
    for (int j = 0; j < NJ; ++j)
        afull[j] = *(const bf16x8*)(wl + ((kg * 161) + j * 16 + bl) * 8);
    bf16x8 xv = *(const bf16x8*)(xl + (brow * 5 + kg) * 8);

    if (MODE == 0) {
#pragma unroll
        for (int j = 0; j < NJ; ++j)
            sacc[j] = __builtin_amdgcn_mfma_f32_16x16x32_bf16(afull[j], xv, sacc[j], 0, 0, 0);
    } else {
#pragma unroll
        for (int q = 0; q < 4; ++q) {
            const bf16x8 bq = (kg == q) ? xv : zerob;   // isolate i = i0+q
            f32x4 uh[NJ];
#pragma unroll
            for (int j = 0; j < NJ; ++j)
                uh[j] = __builtin_amdgcn_mfma_f32_16x16x32_bf16(afull[j], bq, zero, 0, 0, 0);

            // per-lane partial dots over this lane's 4 d's (f32)
            float bd[NJ];
#pragma unroll
            for (int j = 0; j < NJ; ++j)
                bd[j] = uh[j][0] * vs[j][0] + uh[j][1] * vs[j][1]
                      + uh[j][2] * vs[j][2] + uh[j][3] * vs[j][3];

            // fp16x2-packed butterfly over the 4 d-quad lane groups:
            // 10 shfl + 10 pk_add.
            h16x2 pk[5];
#pragma unroll
            for (int jp = 0; jp < 5; ++jp)
                pk[jp] = __builtin_amdgcn_cvt_pkrtz(bd[2 * jp], bd[2 * jp + 1]);
#pragma unroll
            for (int jp = 0; jp < 5; ++jp) {
                float f = __shfl_xor(__builtin_bit_cast(float, pk[jp]), 16, 64);
                pk[jp] = pk[jp] + __builtin_bit_cast(h16x2, f);
            }
#pragma unroll
            for (int jp = 0; jp < 5; ++jp) {
                float f = __shfl_xor(__builtin_bit_cast(float, pk[jp]), 32, 64);
                pk[jp] = pk[jp] + __builtin_bit_cast(h16x2, f);
            }

            // softmax over j, no max-subtract (|logit| <= ~3, exp safe)
            float e[NJ];
#pragma unroll
            for (int jp = 0; jp < 5; ++jp) {
                e[2 * jp]     = __expf((float)pk[jp][0]);
                e[2 * jp + 1] = __expf((float)pk[jp][1]);
            }
            float Z = ((e[0] + e[1]) + (e[2] + e[3]))
                    + ((e[4] + e[5]) + (e[6] + e[7])) + (e[8] + e[9]);
            const float rZ = 1.f / Z;
#pragma unroll
            for (int j = 0; j < NJ; ++j) {
                const float c = e[j] * rZ;
                sacc[j] += c * uh[j];
            }
        }
    }

    // epilogue: sacc -> bf16 LDS bounce -> dense contiguous bf16 partials
    __syncthreads();
    unsigned short* s16 = (unsigned short*)smem;   // [64][168]
#pragma unroll
    for (int j = 0; j < NJ; ++j) {
        ushort4 o;
        o.x = f2bf(sacc[j][0]); o.y = f2bf(sacc[j][1]);
        o.z = f2bf(sacc[j][2]); o.w = f2bf(sacc[j][3]);
        *(ushort4*)(s16 + brow * 168 + j * 16 + kg * 4) = o;
    }
    __syncthreads();
    unsigned short* pp = part + ((size_t)ig * NB + b0) * 160;
#pragma unroll
    for (int r = 0; r < 5; ++r) {
        int idx = tid + r * 256;                 // 1280 ushort8 chunks = 64x160
        int row = idx / 20, ch = idx - row * 20;
        *(u16x8*)(pp + idx * 8) = *(const u16x8*)(s16 + row * 168 + ch * 8);
    }
}

// Sum 288 bf16 ig-partials, scale, squash over d (16-lane shfl), update vsum/out.
__global__ __launch_bounds__(256)
void squash_reduce(const unsigned short* __restrict__ part,
                   float* __restrict__ vsum_g, float* __restrict__ out,
                   float alpha, int mode)
{
    const int t = blockIdx.x * 256 + threadIdx.x;   // < 81920 = b*160 + j*16 + d
    const unsigned short* p = part + t;
    float a0 = 0.f, a1 = 0.f, a2 = 0.f, a3 = 0.f;
#pragma unroll 4
    for (int ig = 0; ig < NIG4; ig += 4) {
        a0 += bf2f(p[(size_t)ig * 81920]);
        a1 += bf2f(p[(size_t)(ig + 1) * 81920]);
        a2 += bf2f(p[(size_t)(ig + 2) * 81920]);
        a3 += bf2f(p[(size_t)(ig + 3) * 81920]);
    }
    const float s = ((a0 + a1) + (a2 + a3)) * alpha;

    float sq = s * s;
    sq += __shfl_xor(sq, 1, 64);
    sq += __shfl_xor(sq, 2, 64);
    sq += __shfl_xor(sq, 4, 64);
    sq += __shfl_xor(sq, 8, 64);
    const float sc = sq / ((1.f + sq) * sqrtf(sq + EPS_));
    const float v  = sc * s;

    if (mode == 0)      vsum_g[t] = v;
    else if (mode == 1) vsum_g[t] += v;
    else                out[t] = v;
}

extern "C" void kernel_launch(void* const* d_in, const int* in_sizes, int n_in,
                              void* d_out, int out_size, void* d_ws, size_t ws_size,
                              hipStream_t stream)
{
    const float* inp = (const float*)d_in[0];
    const float* Wg  = (const float*)d_in[1];
    float* out = (float*)d_out;

    unsigned short* xbp  = (unsigned short*)d_ws;
    unsigned short* wbp  = xbp + XB_ELEMS;
    unsigned short* part = wbp + WB_ELEMS;                    // [288][512][160] bf16
    float* vsum = (float*)(part + (size_t)NIG4 * NB * 160);   // [512][10][16] f32

    conv_bf16<<<(XQ + WQ + 255) / 256, 256, 0, stream>>>(inp, Wg, xbp, wbp);

    dim3 grid(8, NIG4);   // (8,288) = 2304 blocks, 4 i's each
    // iter 0: c uniform 1/10 (folded into alpha); K=32 contracts 4 i's exactly
    caps_pass<0><<<grid, 256, 0, stream>>>(xbp, wbp, nullptr, part);
    squash_reduce<<<320, 256, 0, stream>>>(part, vsum, out, 0.1f, 0);
    // iter 1: logits = u_hat . v0
    caps_pass<1><<<grid, 256, 0, stream>>>(xbp, wbp, vsum, part);
    squash_reduce<<<320, 256, 0, stream>>>(part, vsum, out, 1.0f, 1);
    // iter 2: logits = u_hat . (v0+v1)
    caps_pass<1><<<grid, 256, 0, stream>>>(xbp, wbp, vsum, part);
    squash_reduce<<<320, 256, 0, stream>>>(part, vsum, out, 1.0f, 2);
}

// Round 5
// 157.521 us; speedup vs baseline: 1.1022x; 1.1022x over previous
//
#include <hip/hip_runtime.h>

// DigiCaps dynamic routing — R24: barrier-free, LDS-free caps_pass.
// inputs [512,1152,8] f32, W [10,1152,16,8] f32, out v [512,10,16] f32.
// u_hat[b,j,i,d] = sum_k x[b,i,k] W[j,i,d,k]; logits via vsum recurrence;
// u_hat never materialized (3 recompute passes).
//
// Evidence trail:
//  R20: reg-held prefetch -> spill artifact (FETCH 338MB).
//  R21: (512,4) VGPR cap 64 -> spill artifact (FETCH 266MB).
//  R22: 288 blocks x4 work -> caps ~44us. R23: 2304 blocks x0.5 work ->
//       caps ~41us. With R18 (1152, 1x, 47us): pass time is INSENSITIVE to
//       block count and per-block work over 8x range; effective residency
//       ~1.4 blocks/CU though static limits allow 4-5. Blocks run near-
//       serially per CU -> the barrier-locksteped block IS the scheduling
//       quantum. Fix: remove the lockstep.
// R24: W (2.95MB bf16) and vsum (0.33MB) fit per-XCD L2 -> LDS staging is
// pure overhead. Per-j afull footprint = contiguous 1KB of W[j,i0..i0+3];
// xv = 16x 64B lines; stores direct to part. NO __shared__, NO barriers,
// 4 independent waves/block, grid (8,144) identical to R18 (clean A/B).
// W re-read 32x = 94MB served from L2; HBM FETCH should stay ~15-20MB
// (that, plus VGPR in [150,256], is the spill gate for interpreting timing).
// Carried: MFMA f32_16x16x32_bf16 (C: lane&15=b-col, (lane>>4)*4+reg=d-row);
// K=32 packs 4 i's (all lanes real); MODE1 isolates i=q by masking B;
// fp16x2 logit butterfly; no max-subtract; bf16 pre-convert kernel;
// part [144][512][160] bf16 + squash_reduce as proven (156us baseline).
// absmax prior 3.9e-3 (threshold 17.5e-3) — math identical to R18.

#define NB 512
#define NI 1152
#define NJ 10
#define ND 16
#define NIGB 144   // i-groups of 8

typedef short          bf16x8 __attribute__((ext_vector_type(8)));
typedef unsigned short u16x8  __attribute__((ext_vector_type(8)));
typedef float          f32x4  __attribute__((ext_vector_type(4)));
typedef __fp16         h16x2  __attribute__((ext_vector_type(2)));

constexpr float EPS_ = 1e-7f;

constexpr size_t XB_ELEMS = (size_t)NB * NI * 8;       // bf16
constexpr size_t WB_ELEMS = (size_t)NJ * NI * ND * 8;  // bf16
constexpr int    XQ = 1179648;                         // x float4 quads
constexpr int    WQ = 368640;                          // W float4 quads

__device__ inline unsigned short f2bf(float f) {   // RNE f32->bf16
    unsigned u = __float_as_uint(f);
    return (unsigned short)((u + 0x7fffu + ((u >> 16) & 1u)) >> 16);
}
__device__ inline float bf2f(unsigned short u) {
    return __uint_as_float((unsigned)u << 16);
}

__global__ __launch_bounds__(256)
void conv_bf16(const float* __restrict__ x, const float* __restrict__ Wg,
               unsigned short* __restrict__ xb, unsigned short* __restrict__ wb)
{
    int t = blockIdx.x * 256 + threadIdx.x;
    if (t < XQ) {
        float4 v = ((const float4*)x)[t];
        ushort4 o; o.x=f2bf(v.x); o.y=f2bf(v.y); o.z=f2bf(v.z); o.w=f2bf(v.w);
        ((ushort4*)xb)[t] = o;
    } else if (t - XQ < WQ) {
        int u = t - XQ;
        float4 v = ((const float4*)Wg)[u];
        ushort4 o; o.x=f2bf(v.x); o.y=f2bf(v.y); o.z=f2bf(v.z); o.w=f2bf(v.w);
        ((ushort4*)wb)[u] = o;
    }
}

// Block: 4 independent waves; each wave owns 16 b x 8 i. No LDS, no barriers.
// wb layout [j][i][d][k]: granule (16B) addr = ((j*NI + i)*16 + d) * 8 shorts.
template <int MODE>
__global__ __launch_bounds__(256, 2)
void caps_pass(const unsigned short* __restrict__ xb,
               const unsigned short* __restrict__ wb,
               const float* __restrict__ vsum_g,
               unsigned short* __restrict__ part)
{
    const int tid = threadIdx.x, lane = tid & 63, w = tid >> 6;
    const int bl = lane & 15, kg = lane >> 4;
    const int bg = blockIdx.x, ig = blockIdx.y;
    const int i0 = ig * 8, b0 = bg * 64;
    const int b  = b0 + w * 16 + bl;

    f32x4 vs[NJ];
    if (MODE == 1) {
#pragma unroll
        for (int j = 0; j < NJ; ++j)
            vs[j] = *(const f32x4*)(vsum_g + (size_t)b * 160 + j * 16 + kg * 4);
    }

    const f32x4  zero  = {0.f, 0.f, 0.f, 0.f};
    const bf16x8 zerob = {0, 0, 0, 0, 0, 0, 0, 0};
    f32x4 sacc[NJ];
#pragma unroll
    for (int j = 0; j < NJ; ++j) sacc[j] = zero;

#pragma unroll
    for (int t4 = 0; t4 < 2; ++t4) {
        const int il = i0 + t4 * 4 + kg;   // this lane's input capsule
        // A-frags direct from global (L2-resident W): per j, the wave's 64
        // lanes cover W[j, i0+t4*4 .. +3, 0:16, 0:8] = contiguous 1KB.
        const unsigned short* wbase = wb + (size_t)il * 128 + bl * 8;
        bf16x8 afull[NJ];
#pragma unroll
        for (int j = 0; j < NJ; ++j)
            afull[j] = *(const bf16x8*)(wbase + (size_t)j * (NI * 128));
        // B-frag: x[b, il, 0:8] — per (w,kg) quad the wave reads 16 64B lines.
        bf16x8 xv = *(const bf16x8*)(xb + ((size_t)b * NI + il) * 8);

        if (MODE == 0) {
#pragma unroll
            for (int j = 0; j < NJ; ++j)
                sacc[j] = __builtin_amdgcn_mfma_f32_16x16x32_bf16(afull[j], xv, sacc[j], 0, 0, 0);
        } else {
#pragma unroll
            for (int q = 0; q < 4; ++q) {
                const bf16x8 bq = (kg == q) ? xv : zerob;   // isolate i = i0+t4*4+q
                f32x4 uh[NJ];
#pragma unroll
                for (int j = 0; j < NJ; ++j)
                    uh[j] = __builtin_amdgcn_mfma_f32_16x16x32_bf16(afull[j], bq, zero, 0, 0, 0);

                // per-lane partial dots over this lane's 4 d's (f32)
                float bd[NJ];
#pragma unroll
                for (int j = 0; j < NJ; ++j)
                    bd[j] = uh[j][0] * vs[j][0] + uh[j][1] * vs[j][1]
                          + uh[j][2] * vs[j][2] + uh[j][3] * vs[j][3];

                // fp16x2-packed butterfly over the 4 d-quad lane groups:
                // 10 shfl + 10 pk_add.
                h16x2 pk[5];
#pragma unroll
                for (int jp = 0; jp < 5; ++jp)
                    pk[jp] = __builtin_amdgcn_cvt_pkrtz(bd[2 * jp], bd[2 * jp + 1]);
#pragma unroll
                for (int jp = 0; jp < 5; ++jp) {
                    float f = __shfl_xor(__builtin_bit_cast(float, pk[jp]), 16, 64);
                    pk[jp] = pk[jp] + __builtin_bit_cast(h16x2, f);
                }
#pragma unroll
                for (int jp = 0; jp < 5; ++jp) {
                    float f = __shfl_xor(__builtin_bit_cast(float, pk[jp]), 32, 64);
                    pk[jp] = pk[jp] + __builtin_bit_cast(h16x2, f);
                }

                // softmax over j, no max-subtract (|logit| <= ~3, exp safe)
                float e[NJ];
#pragma unroll
                for (int jp = 0; jp < 5; ++jp) {
                    e[2 * jp]     = __expf((float)pk[jp][0]);
                    e[2 * jp + 1] = __expf((float)pk[jp][1]);
                }
                float Z = ((e[0] + e[1]) + (e[2] + e[3]))
                        + ((e[4] + e[5]) + (e[6] + e[7])) + (e[8] + e[9]);
                const float rZ = 1.f / Z;
#pragma unroll
                for (int j = 0; j < NJ; ++j) {
                    const float c = e[j] * rZ;
                    sacc[j] += c * uh[j];
                }
            }
        }
    }

    // epilogue: direct bf16 stores; lane (kg,bl) owns part[ig][b][j*16+kg*4..+4].
    // Per store-instr the wave covers 16 rows x 32B contiguous; the j-unroll
    // fully covers each 64B line back-to-back (L2 write-merge).
    unsigned short* pp = part + ((size_t)ig * NB + b) * 160;
#pragma unroll
    for (int j = 0; j < NJ; ++j) {
        ushort4 o;
        o.x = f2bf(sacc[j][0]); o.y = f2bf(sacc[j][1]);
        o.z = f2bf(sacc[j][2]); o.w = f2bf(sacc[j][3]);
        *(ushort4*)(pp + j * 16 + kg * 4) = o;
    }
}

// Sum 144 bf16 ig-partials, scale, squash over d (16-lane shfl), update vsum/out.
__global__ __launch_bounds__(256)
void squash_reduce(const unsigned short* __restrict__ part,
                   float* __restrict__ vsum_g, float* __restrict__ out,
                   float alpha, int mode)
{
    const int t = blockIdx.x * 256 + threadIdx.x;   // < 81920 = b*160 + j*16 + d
    const unsigned short* p = part + t;
    float a0 = 0.f, a1 = 0.f, a2 = 0.f, a3 = 0.f;
#pragma unroll 4
    for (int ig = 0; ig < NIGB; ig += 4) {
        a0 += bf2f(p[(size_t)ig * 81920]);
        a1 += bf2f(p[(size_t)(ig + 1) * 81920]);
        a2 += bf2f(p[(size_t)(ig + 2) * 81920]);
        a3 += bf2f(p[(size_t)(ig + 3) * 81920]);
    }
    const float s = ((a0 + a1) + (a2 + a3)) * alpha;

    float sq = s * s;
    sq += __shfl_xor(sq, 1, 64);
    sq += __shfl_xor(sq, 2, 64);
    sq += __shfl_xor(sq, 4, 64);
    sq += __shfl_xor(sq, 8, 64);
    const float sc = sq / ((1.f + sq) * sqrtf(sq + EPS_));
    const float v  = sc * s;

    if (mode == 0)      vsum_g[t] = v;
    else if (mode == 1) vsum_g[t] += v;
    else                out[t] = v;
}

extern "C" void kernel_launch(void* const* d_in, const int* in_sizes, int n_in,
                              void* d_out, int out_size, void* d_ws, size_t ws_size,
                              hipStream_t stream)
{
    const float* inp = (const float*)d_in[0];
    const float* Wg  = (const float*)d_in[1];
    float* out = (float*)d_out;

    unsigned short* xbp  = (unsigned short*)d_ws;
    unsigned short* wbp  = xbp + XB_ELEMS;
    unsigned short* part = wbp + WB_ELEMS;                    // [144][512][160] bf16
    float* vsum = (float*)(part + (size_t)NIGB * NB * 160);   // [512][10][16] f32

    conv_bf16<<<(XQ + WQ + 255) / 256, 256, 0, stream>>>(inp, Wg, xbp, wbp);

    dim3 grid(8, NIGB);   // (8,144) = 1152 blocks — identical to R18 (A/B)
    // iter 0: c uniform 1/10 (folded into alpha); K=32 contracts 4 i's exactly
    caps_pass<0><<<grid, 256, 0, stream>>>(xbp, wbp, nullptr, part);
    squash_reduce<<<320, 256, 0, stream>>>(part, vsum, out, 0.1f, 0);
    // iter 1: logits = u_hat . v0
    caps_pass<1><<<grid, 256, 0, stream>>>(xbp, wbp, vsum, part);
    squash_reduce<<<320, 256, 0, stream>>>(part, vsum, out, 1.0f, 1);
    // iter 2: logits = u_hat . (v0+v1)
    caps_pass<1><<<grid, 256, 0, stream>>>(xbp, wbp, vsum, part);
    squash_reduce<<<320, 256, 0, stream>>>(part, vsum, out, 1.0f, 2);
}